// Round 1
// baseline (707.477 us; speedup 1.0000x reference)
//
#include <hip/hip_runtime.h>

#define B_ 64
#define S_ 1024
#define NT 48
#define DM 512
#define TT 50

// ---------------- K1: tag_vec = F @ W^T / sqrt(512) ----------------
__global__ __launch_bounds__(256) void k_tagvec(const float* __restrict__ F,
                                                const float* __restrict__ Wm,
                                                float* __restrict__ out) {
  __shared__ float fs[128][68];
  __shared__ float wsh[48][68];
  const int t = threadIdx.x;
  const int rowBase = blockIdx.x * 128;
  const int jg = t & 3;   // 4 col-groups of 12
  const int rq = t >> 2;  // 0..63 -> 2 rows each
  const int r0 = rq * 2, r1 = r0 + 1;
  float acc0[12];
  float acc1[12];
#pragma unroll
  for (int q = 0; q < 12; ++q) { acc0[q] = 0.f; acc1[q] = 0.f; }
  for (int kc = 0; kc < DM; kc += 64) {
    __syncthreads();
#pragma unroll
    for (int i2 = 0; i2 < 8; ++i2) {
      int f = t + i2 * 256;       // 0..2047
      int row = f >> 4, kk = f & 15;
      float4 v = *(const float4*)(F + (size_t)(rowBase + row) * DM + kc + kk * 4);
      *(float4*)&fs[row][kk * 4] = v;
    }
#pragma unroll
    for (int i2 = 0; i2 < 3; ++i2) {
      int f = t + i2 * 256;       // 0..767
      int row = f >> 4, kk = f & 15;
      float4 v = *(const float4*)(Wm + (size_t)row * DM + kc + kk * 4);
      *(float4*)&wsh[row][kk * 4] = v;
    }
    __syncthreads();
#pragma unroll 4
    for (int k4 = 0; k4 < 16; ++k4) {
      float4 a0 = *(const float4*)&fs[r0][k4 * 4];
      float4 a1 = *(const float4*)&fs[r1][k4 * 4];
#pragma unroll
      for (int jj = 0; jj < 12; ++jj) {
        float4 w = *(const float4*)&wsh[jg * 12 + jj][k4 * 4];
        acc0[jj] += a0.x * w.x + a0.y * w.y + a0.z * w.z + a0.w * w.w;
        acc1[jj] += a1.x * w.x + a1.y * w.y + a1.z * w.z + a1.w * w.w;
      }
    }
  }
  const float sc = 0.044194173824159216f;  // 1/sqrt(512)
  size_t base0 = (size_t)(rowBase + r0) * NT + jg * 12;
  size_t base1 = (size_t)(rowBase + r1) * NT + jg * 12;
#pragma unroll
  for (int q = 0; q < 3; ++q) {
    float4 o0 = make_float4(acc0[q*4]*sc, acc0[q*4+1]*sc, acc0[q*4+2]*sc, acc0[q*4+3]*sc);
    float4 o1 = make_float4(acc1[q*4]*sc, acc1[q*4+1]*sc, acc1[q*4+2]*sc, acc1[q*4+3]*sc);
    *(float4*)(out + base0 + q*4) = o0;
    *(float4*)(out + base1 + q*4) = o1;
  }
}

// ---------------- K2: gold-path score per batch ----------------
__global__ __launch_bounds__(256) void k_score(const float* __restrict__ tg,
                                               const int* __restrict__ y,
                                               const unsigned char* __restrict__ mask,
                                               const float* __restrict__ trans,
                                               float* __restrict__ scoreOut) {
  const int b = blockIdx.x, t = threadIdx.x;
  const int* yb = y + (size_t)b * S_;
  const unsigned char* mbp = mask + (size_t)b * S_;
  float part = 0.f;
  int cnt = 0;
  for (int s = t; s < S_; s += 256) {
    int ys = yb[s];
    int ms = mbp[s];
    float bm = ms ? 0.f : 1.f;
    int yy = ms ? 0 : ys;
    part += tg[((size_t)b * S_ + s) * NT + yy] * bm;
    if (s >= 1) part += trans[yb[s - 1] * TT + ys] * bm;
    cnt += ms ? 1 : 0;
  }
  for (int d = 1; d < 64; d <<= 1) {
    part += __shfl_xor(part, d);
    cnt += __shfl_xor(cnt, d);
  }
  __shared__ float pw[4];
  __shared__ int cw[4];
  int wid = t >> 6;
  if ((t & 63) == 0) { pw[wid] = part; cw[wid] = cnt; }
  __syncthreads();
  if (t == 0) {
    float tot = pw[0] + pw[1] + pw[2] + pw[3];
    int c = cw[0] + cw[1] + cw[2] + cw[3];
    int L = S_ - 1 - c;
    tot += trans[NT * TT + yb[0]];        // start[y0]
    tot += trans[yb[L] * TT + (NT + 1)];  // end[y_L]
    scoreOut[b] = tot;
  }
}

// ---------------- K3: forward logsumexp (blocks 0..63) + Viterbi (blocks 64..127) ----------------
__global__ __launch_bounds__(768) void k_scan(const float* __restrict__ tg,
                                              const unsigned char* __restrict__ mask,
                                              const float* __restrict__ trans,
                                              const float* __restrict__ score,
                                              float* __restrict__ out) {
  __shared__ float eL[2][NT];
  __shared__ float pL[2][NT];
  __shared__ float finalB[NT];
  __shared__ unsigned char mb[S_];
  __shared__ int ELs[16];
  __shared__ int ints[2];  // [0]=mask count, [1]=now0
  __shared__ unsigned char mapc[16][NT];
  __shared__ unsigned char idxL[S_][NT];  // stage_idx (viterbi only)

  const int t = threadIdx.x;
  const bool isV = (blockIdx.x >= B_);
  const int b = isV ? (blockIdx.x - B_) : blockIdx.x;
  const int j = t >> 4;        // 0..47
  const int ig = t & 15;       // 0..15
  const int i0 = ig * 3;       // 3 i's per thread
  const float T0 = trans[(i0 + 0) * TT + j];
  const float T1 = trans[(i0 + 1) * TT + j];
  const float T2 = trans[(i0 + 2) * TT + j];

  if (t == 0) ints[0] = 0;
  __syncthreads();
  int lc = 0;
  for (int m = t; m < S_; m += 768) {
    unsigned char mv = mask[(size_t)b * S_ + m];
    mb[m] = mv;
    lc += mv ? 1 : 0;
  }
  for (int d = 1; d < 64; d <<= 1) lc += __shfl_xor(lc, d);
  if ((t & 63) == 0 && lc) atomicAdd(&ints[0], lc);

  float e_next = 0.f;
  if (t < NT) {
    eL[0][t] = tg[((size_t)b * S_ + 0) * NT + t];
    e_next   = tg[((size_t)b * S_ + 1) * NT + t];
    pL[0][t] = trans[NT * TT + t];  // start
  }
  __syncthreads();
  const int L = S_ - 1 - ints[0];

  if (!isV) {
    // ---- forward logsumexp scan ----
    for (int s = 0; s < S_; ++s) {
      const int cur = s & 1, nxt = cur ^ 1;
      const float m0 = mb[s] ? 0.f : 1.f;
      const float m1 = (s + 1 < S_) ? (mb[s + 1] ? 0.f : 1.f) : 0.f;
      float a0 = pL[cur][i0]     + eL[cur][i0]     * m0;
      float a1 = pL[cur][i0 + 1] + eL[cur][i0 + 1] * m0;
      float a2 = pL[cur][i0 + 2] + eL[cur][i0 + 2] * m0;
      float v0 = a0 + T0 * m1;
      float v1 = a1 + T1 * m1;
      float v2 = a2 + T2 * m1;
      float M = fmaxf(v0, fmaxf(v1, v2));
      for (int d = 1; d < 16; d <<= 1) M = fmaxf(M, __shfl_xor(M, d));
      float sum = __expf(v0 - M) + __expf(v1 - M) + __expf(v2 - M);
      for (int d = 1; d < 16; d <<= 1) sum += __shfl_xor(sum, d);
      if (ig == 0) pL[nxt][j] = M + __logf(sum);
      if (t < NT && s + 1 < S_) {
        eL[nxt][t] = e_next;
        if (s + 2 < S_) e_next = tg[((size_t)b * S_ + s + 2) * NT + t];
      }
      __syncthreads();
    }
    if (t < 64) {
      float v = (t < NT) ? pL[0][t] + trans[t * TT + (NT + 1)] : -3.0e38f;
      float M = v;
      for (int d = 1; d < 64; d <<= 1) M = fmaxf(M, __shfl_xor(M, d));
      float sum = __expf(v - M);
      for (int d = 1; d < 64; d <<= 1) sum += __shfl_xor(sum, d);
      if (t == 0) out[b] = (M + __logf(sum)) - score[b];
    }
  } else {
    // ---- Viterbi ----
    if (t < NT) {
      float b0 = trans[NT * TT + t] + eL[0][t];
      pL[1][t] = b0;
      if (L == 0) finalB[t] = b0;
      eL[1][t] = e_next;
      e_next = tg[((size_t)b * S_ + 2) * NT + t];
    }
    __syncthreads();
    for (int s = 1; s < S_; ++s) {
      const int cur = s & 1, nxt = cur ^ 1;
      float c0 = pL[cur][i0]     + T0;
      float c1 = pL[cur][i0 + 1] + T1;
      float c2 = pL[cur][i0 + 2] + T2;
      float bv = c0; int bi = i0;
      if (c1 > bv) { bv = c1; bi = i0 + 1; }
      if (c2 > bv) { bv = c2; bi = i0 + 2; }
      for (int d = 1; d < 16; d <<= 1) {
        float vo = __shfl_xor(bv, d);
        int io = __shfl_xor(bi, d);
        if (vo > bv || (vo == bv && io < bi)) { bv = vo; bi = io; }
      }
      if (ig == 0) {
        float bnew = bv + eL[cur][j];
        pL[nxt][j] = bnew;
        idxL[s][j] = (unsigned char)bi;
        if (s == L) finalB[j] = bnew;
      }
      if (t < NT && s + 1 < S_) {
        eL[nxt][t] = e_next;
        if (s + 2 < S_) e_next = tg[((size_t)b * S_ + s + 2) * NT + t];
      }
      __syncthreads();
    }
    // now0 = argmax_j(finalB[j] + end[j]) with first-index tie-break
    if (t < 64) {
      float v = (t < NT) ? finalB[t] + trans[t * TT + (NT + 1)] : -3.0e38f;
      int bj = (t < NT) ? t : 63;
      for (int d = 1; d < 64; d <<= 1) {
        float vo = __shfl_xor(v, d);
        int io = __shfl_xor(bj, d);
        if (vo > v || (vo == v && io < bj)) { v = vo; bj = io; }
      }
      if (t == 0) ints[1] = bj;
    }
    __syncthreads();
    const int now0 = ints[1];
    // phase 1: chunk maps (16 chunks x 48 start tags)
    {
      const int c = t / NT;          // 0..15
      const int jj2 = t - c * NT;    // 0..47
      int cur2 = jj2;
      const int top = (c == 15) ? (S_ - 1) : (c + 1) * 64;
      const int base = c * 64;
      for (int m = top; m > base; --m) {
        if (m <= L) cur2 = idxL[m][cur2];
      }
      mapc[c][jj2] = (unsigned char)cur2;
    }
    __syncthreads();
    // phase 2: chunk entry tags
    if (t == 0) {
      int e = now0;
      ELs[15] = e;
      for (int c2 = 15; c2 >= 1; --c2) {
        e = mapc[c2][e];
        ELs[c2 - 1] = e;
      }
    }
    __syncthreads();
    // phase 3: re-walk the needed chain per chunk, write path
    float* pathOut = out + B_ + (size_t)b * S_;
    if (t < 16) {
      const int c = t;
      const int top = (c == 15) ? (S_ - 1) : (c + 1) * 64;
      const int base = c * 64;
      int cur2 = ELs[c];
      for (int m = top; m > base; --m) {
        if (m <= L) cur2 = idxL[m][cur2];
        int pos = m - 1;
        pathOut[pos] = (pos > L) ? -1.0f : (float)cur2;
      }
    }
    if (t == 0) {
      pathOut[S_ - 1] = (L == S_ - 1) ? (float)now0 : -1.0f;
    }
  }
}

extern "C" void kernel_launch(void* const* d_in, const int* in_sizes, int n_in,
                              void* d_out, int out_size, void* d_ws, size_t ws_size,
                              hipStream_t stream) {
  const float* F = (const float*)d_in[0];
  const int* y = (const int*)d_in[1];
  const unsigned char* mask = (const unsigned char*)d_in[2];
  const float* Wm = (const float*)d_in[3];
  const float* trans = (const float*)d_in[4];
  float* out = (float*)d_out;
  float* tg = (float*)d_ws;                         // 64*1024*48 floats
  float* score = tg + (size_t)B_ * S_ * NT;         // 64 floats

  k_tagvec<<<dim3((B_ * S_) / 128), dim3(256), 0, stream>>>(F, Wm, tg);
  k_score<<<dim3(B_), dim3(256), 0, stream>>>(tg, y, mask, trans, score);
  k_scan<<<dim3(2 * B_), dim3(768), 0, stream>>>(tg, mask, trans, score, out);
}

// Round 2
// 551.390 us; speedup vs baseline: 1.2831x; 1.2831x over previous
//
#include <hip/hip_runtime.h>

#define B_ 64
#define S_ 1024
#define NT 48
#define DM 512
#define TT 50

__device__ __forceinline__ float rl(float v, int lane) {
  return __int_as_float(__builtin_amdgcn_readlane(__float_as_int(v), lane));
}
__device__ __forceinline__ float rfl(float v) {
  return __int_as_float(__builtin_amdgcn_readfirstlane(__float_as_int(v)));
}

// ---------------- K1: tag_vec = F @ W^T / sqrt(512) ----------------
__global__ __launch_bounds__(256) void k_tagvec(const float* __restrict__ F,
                                                const float* __restrict__ Wm,
                                                float* __restrict__ out) {
  __shared__ float fs[128][68];
  __shared__ float wsh[48][68];
  const int t = threadIdx.x;
  const int rowBase = blockIdx.x * 128;
  const int jg = t & 3;
  const int rq = t >> 2;
  const int r0 = rq * 2, r1 = r0 + 1;
  float acc0[12];
  float acc1[12];
#pragma unroll
  for (int q = 0; q < 12; ++q) { acc0[q] = 0.f; acc1[q] = 0.f; }
  for (int kc = 0; kc < DM; kc += 64) {
    __syncthreads();
#pragma unroll
    for (int i2 = 0; i2 < 8; ++i2) {
      int f = t + i2 * 256;
      int row = f >> 4, kk = f & 15;
      float4 v = *(const float4*)(F + (size_t)(rowBase + row) * DM + kc + kk * 4);
      *(float4*)&fs[row][kk * 4] = v;
    }
#pragma unroll
    for (int i2 = 0; i2 < 3; ++i2) {
      int f = t + i2 * 256;
      int row = f >> 4, kk = f & 15;
      float4 v = *(const float4*)(Wm + (size_t)row * DM + kc + kk * 4);
      *(float4*)&wsh[row][kk * 4] = v;
    }
    __syncthreads();
#pragma unroll 4
    for (int k4 = 0; k4 < 16; ++k4) {
      float4 a0 = *(const float4*)&fs[r0][k4 * 4];
      float4 a1 = *(const float4*)&fs[r1][k4 * 4];
#pragma unroll
      for (int jj = 0; jj < 12; ++jj) {
        float4 w = *(const float4*)&wsh[jg * 12 + jj][k4 * 4];
        acc0[jj] += a0.x * w.x + a0.y * w.y + a0.z * w.z + a0.w * w.w;
        acc1[jj] += a1.x * w.x + a1.y * w.y + a1.z * w.z + a1.w * w.w;
      }
    }
  }
  const float sc = 0.044194173824159216f;
  size_t base0 = (size_t)(rowBase + r0) * NT + jg * 12;
  size_t base1 = (size_t)(rowBase + r1) * NT + jg * 12;
#pragma unroll
  for (int q = 0; q < 3; ++q) {
    float4 o0 = make_float4(acc0[q*4]*sc, acc0[q*4+1]*sc, acc0[q*4+2]*sc, acc0[q*4+3]*sc);
    float4 o1 = make_float4(acc1[q*4]*sc, acc1[q*4+1]*sc, acc1[q*4+2]*sc, acc1[q*4+3]*sc);
    *(float4*)(out + base0 + q*4) = o0;
    *(float4*)(out + base1 + q*4) = o1;
  }
}

// ---------------- K2: gold-path score per batch ----------------
__global__ __launch_bounds__(256) void k_score(const float* __restrict__ tg,
                                               const int* __restrict__ y,
                                               const unsigned char* __restrict__ mask,
                                               const float* __restrict__ trans,
                                               float* __restrict__ scoreOut) {
  const int b = blockIdx.x, t = threadIdx.x;
  const int* yb = y + (size_t)b * S_;
  const unsigned char* mbp = mask + (size_t)b * S_;
  float part = 0.f;
  int cnt = 0;
  for (int s = t; s < S_; s += 256) {
    int ys = yb[s];
    int ms = mbp[s];
    float bm = ms ? 0.f : 1.f;
    int yy = ms ? 0 : ys;
    part += tg[((size_t)b * S_ + s) * NT + yy] * bm;
    if (s >= 1) part += trans[yb[s - 1] * TT + ys] * bm;
    cnt += ms ? 1 : 0;
  }
  for (int d = 1; d < 64; d <<= 1) {
    part += __shfl_xor(part, d);
    cnt += __shfl_xor(cnt, d);
  }
  __shared__ float pw[4];
  __shared__ int cw[4];
  int wid = t >> 6;
  if ((t & 63) == 0) { pw[wid] = part; cw[wid] = cnt; }
  __syncthreads();
  if (t == 0) {
    float tot = pw[0] + pw[1] + pw[2] + pw[3];
    int c = cw[0] + cw[1] + cw[2] + cw[3];
    int L = S_ - 1 - c;
    tot += trans[NT * TT + yb[0]];
    tot += trans[yb[L] * TT + (NT + 1)];
    scoreOut[b] = tot;
  }
}

// ---------------- K3: single-wave scans; blocks 0..63 forward LSE, 64..127 Viterbi ----------------
__global__ __launch_bounds__(64) void k_scan(const float* __restrict__ tg,
                                             const unsigned char* __restrict__ mask,
                                             const float* __restrict__ trans,
                                             const float* __restrict__ score,
                                             float* __restrict__ out) {
  __shared__ float bmL[S_ + 4];
  __shared__ unsigned char idxL[S_][NT];
  __shared__ unsigned char mapc[16][NT];
  __shared__ int ELs[16];

  const int t = threadIdx.x;
  const bool isV = blockIdx.x >= B_;
  const int b = isV ? (blockIdx.x - B_) : blockIdx.x;
  const int jc = (t < NT) ? t : (NT - 1);
  const float* tgb = tg + (size_t)b * S_ * NT;

  // mask -> bm floats (forward), masked count -> L (viterbi)
  int cnt = 0;
  for (int m = t; m < S_; m += 64) {
    unsigned char mv = mask[(size_t)b * S_ + m];
    bmL[m] = mv ? 0.f : 1.f;
    cnt += mv ? 1 : 0;
  }
  if (t < 4) bmL[S_ + t] = 0.f;
#pragma unroll
  for (int d = 1; d < 64; d <<= 1) cnt += __shfl_xor(cnt, d);
  const int L = S_ - 1 - cnt;
  __syncthreads();

  if (!isV) {
    // ---------- forward logsumexp scan (single wave) ----------
    float Ecol[NT];
#pragma unroll
    for (int i = 0; i < NT; ++i) Ecol[i] = __expf(trans[i * TT + jc]);
    float q = trans[NT * TT + jc];  // start[j], shifted state
    float C = 0.f;                  // accumulated uniform offset
    float ec = tgb[0 * NT + jc];
    float en = tgb[1 * NT + jc];
    float m0r = bmL[0], m1r = bmL[1];
    for (int s = 0; s < S_; ++s) {
      float a = fmaf(ec, m0r, q);
      float p = __expf(a);
      ec = en;
      int s2 = (s + 2 < S_) ? (s + 2) : (S_ - 1);
      en = tgb[(size_t)s2 * NT + jc];
      float nm0 = m1r;
      float m1n = bmL[s + 2];
      int m1bits = __builtin_amdgcn_readfirstlane(__float_as_int(m1r));
      float z0 = 0.f, z1 = 0.f, z2 = 0.f, z3 = 0.f;
      if (m1bits != 0) {
#pragma unroll
        for (int i = 0; i < NT; i += 4) {
          z0 = fmaf(rl(p, i + 0), Ecol[i + 0], z0);
          z1 = fmaf(rl(p, i + 1), Ecol[i + 1], z1);
          z2 = fmaf(rl(p, i + 2), Ecol[i + 2], z2);
          z3 = fmaf(rl(p, i + 3), Ecol[i + 3], z3);
        }
      } else {
#pragma unroll
        for (int i = 0; i < NT; i += 4) {
          z0 += rl(p, i + 0);
          z1 += rl(p, i + 1);
          z2 += rl(p, i + 2);
          z3 += rl(p, i + 3);
        }
      }
      float Z = (z0 + z1) + (z2 + z3);
      float tj = __logf(Z);
      float d0 = rfl(tj);
      q = tj - d0;
      C += d0;
      m0r = nm0;
      m1r = m1n;
    }
    // logZ = C + lse_j(q_j + end_j); loss = logZ - score
    float v = (t < NT) ? (q + trans[t * TT + (NT + 1)]) : -3.0e38f;
    float M = v;
#pragma unroll
    for (int d = 1; d < 64; d <<= 1) M = fmaxf(M, __shfl_xor(M, d));
    float sum = (t < NT) ? __expf(v - M) : 0.f;
#pragma unroll
    for (int d = 1; d < 64; d <<= 1) sum += __shfl_xor(sum, d);
    if (t == 0) out[b] = C + M + __logf(sum) - score[b];
  } else {
    // ---------- Viterbi (single wave) ----------
    float Tcol[NT];
#pragma unroll
    for (int i = 0; i < NT; ++i) Tcol[i] = trans[i * TT + jc];
    float e0 = tgb[0 * NT + jc];
    float best = trans[NT * TT + jc] + e0;  // start[j] + e0[j]
    float fin = best;                       // valid if L==0
    float ec = tgb[1 * NT + jc];
    float en = tgb[2 * NT + jc];
    for (int s = 1; s < S_; ++s) {
      float c[NT];
#pragma unroll
      for (int i = 0; i < NT; ++i) c[i] = rl(best, i) + Tcol[i];
      // value max via max3 tree (exact: returns one of the inputs)
      float t16[16];
#pragma unroll
      for (int k = 0; k < 16; ++k)
        t16[k] = fmaxf(fmaxf(c[3 * k], c[3 * k + 1]), c[3 * k + 2]);
      float t6a = fmaxf(fmaxf(t16[0], t16[1]), t16[2]);
      float t6b = fmaxf(fmaxf(t16[3], t16[4]), t16[5]);
      float t6c = fmaxf(fmaxf(t16[6], t16[7]), t16[8]);
      float t6d = fmaxf(fmaxf(t16[9], t16[10]), t16[11]);
      float t6e = fmaxf(fmaxf(t16[12], t16[13]), t16[14]);
      float t6f = t16[15];
      float x = fmaxf(fmaxf(t6a, t6b), t6c);
      float yv = fmaxf(fmaxf(t6d, t6e), t6f);
      float M = fmaxf(x, yv);
      // first-index argmax: 4 parallel downward scans + min merge
      int i0 = 99, i1 = 99, i2 = 99, i3 = 99;
#pragma unroll
      for (int k = 11; k >= 0; --k) {
        i0 = (c[k] == M) ? k : i0;
        i1 = (c[12 + k] == M) ? (12 + k) : i1;
        i2 = (c[24 + k] == M) ? (24 + k) : i2;
        i3 = (c[36 + k] == M) ? (36 + k) : i3;
      }
      int idx = min(min(i0, i1), min(i2, i3));
      float bnew = M + ec;  // max first, then +e (matches passing round-1 arithmetic)
      idxL[s][jc] = (unsigned char)idx;
      fin = (s == L) ? bnew : fin;
      best = bnew;
      ec = en;
      int s2 = (s + 2 < S_) ? (s + 2) : (S_ - 1);
      en = tgb[(size_t)s2 * NT + jc];
    }
    // now0 = first-index argmax_j(fin_j + end_j)
    float v = (t < NT) ? (fin + trans[t * TT + (NT + 1)]) : -3.0e38f;
    float M = v;
#pragma unroll
    for (int d = 1; d < 64; d <<= 1) M = fmaxf(M, __shfl_xor(M, d));
    unsigned long long ball = __ballot(v == M);
    int now0 = __ffsll((unsigned long long)ball) - 1;
    __syncthreads();
    // phase 1: 16 chunk maps x 48 tags = 768 walks, 12 interleaved per lane
    int cur[12], topA[12], baseA[12];
#pragma unroll
    for (int k = 0; k < 12; ++k) {
      int w = t + 64 * k;
      int cch = (w * 683) >> 15;  // w/48 for w<768
      int g = w - cch * 48;
      cur[k] = g;
      topA[k] = (cch == 15) ? (S_ - 1) : (cch + 1) * 64;
      baseA[k] = cch * 64;
    }
    for (int step = 0; step < 64; ++step) {
#pragma unroll
      for (int k = 0; k < 12; ++k) {
        int m = topA[k] - step;
        if (m > baseA[k] && m <= L) cur[k] = idxL[m][cur[k]];
      }
    }
#pragma unroll
    for (int k = 0; k < 12; ++k) {
      int w = t + 64 * k;
      int cch = (w * 683) >> 15;
      int g = w - cch * 48;
      mapc[cch][g] = (unsigned char)cur[k];
    }
    __syncthreads();
    // phase 2: chunk entry tags
    if (t == 0) {
      int e = now0;
      ELs[15] = e;
      for (int c2 = 15; c2 >= 1; --c2) {
        e = mapc[c2][e];
        ELs[c2 - 1] = e;
      }
    }
    __syncthreads();
    // phase 3: re-walk needed chain per chunk, write path
    float* pathOut = out + B_ + (size_t)b * S_;
    if (t < 16) {
      const int cch = t;
      const int top = (cch == 15) ? (S_ - 1) : (cch + 1) * 64;
      const int base = cch * 64;
      int cu = ELs[cch];
      for (int m = top; m > base; --m) {
        if (m <= L) cu = idxL[m][cu];
        int pos = m - 1;
        pathOut[pos] = (pos > L) ? -1.0f : (float)cu;
      }
    }
    if (t == 0) pathOut[S_ - 1] = (L == S_ - 1) ? (float)now0 : -1.0f;
  }
}

extern "C" void kernel_launch(void* const* d_in, const int* in_sizes, int n_in,
                              void* d_out, int out_size, void* d_ws, size_t ws_size,
                              hipStream_t stream) {
  const float* F = (const float*)d_in[0];
  const int* y = (const int*)d_in[1];
  const unsigned char* mask = (const unsigned char*)d_in[2];
  const float* Wm = (const float*)d_in[3];
  const float* trans = (const float*)d_in[4];
  float* out = (float*)d_out;
  float* tg = (float*)d_ws;
  float* score = tg + (size_t)B_ * S_ * NT;

  k_tagvec<<<dim3((B_ * S_) / 128), dim3(256), 0, stream>>>(F, Wm, tg);
  k_score<<<dim3(B_), dim3(256), 0, stream>>>(tg, y, mask, trans, score);
  k_scan<<<dim3(2 * B_), dim3(64), 0, stream>>>(tg, mask, trans, score, out);
}

// Round 3
// 463.996 us; speedup vs baseline: 1.5247x; 1.1884x over previous
//
#include <hip/hip_runtime.h>

#define B_ 64
#define S_ 1024
#define NT 48
#define DM 512
#define TT 50

__device__ __forceinline__ float rl(float v, int lane) {
  return __int_as_float(__builtin_amdgcn_readlane(__float_as_int(v), lane));
}

// ---------------- K1: tag_vec = F @ W^T / sqrt(512) ----------------
__global__ __launch_bounds__(256) void k_tagvec(const float* __restrict__ F,
                                                const float* __restrict__ Wm,
                                                float* __restrict__ out) {
  __shared__ float fs[128][68];
  __shared__ float wsh[48][68];
  const int t = threadIdx.x;
  const int rowBase = blockIdx.x * 128;
  const int jg = t & 3;
  const int rq = t >> 2;
  const int r0 = rq * 2, r1 = r0 + 1;
  float acc0[12];
  float acc1[12];
#pragma unroll
  for (int q = 0; q < 12; ++q) { acc0[q] = 0.f; acc1[q] = 0.f; }
  for (int kc = 0; kc < DM; kc += 64) {
    __syncthreads();
#pragma unroll
    for (int i2 = 0; i2 < 8; ++i2) {
      int f = t + i2 * 256;
      int row = f >> 4, kk = f & 15;
      float4 v = *(const float4*)(F + (size_t)(rowBase + row) * DM + kc + kk * 4);
      *(float4*)&fs[row][kk * 4] = v;
    }
#pragma unroll
    for (int i2 = 0; i2 < 3; ++i2) {
      int f = t + i2 * 256;
      int row = f >> 4, kk = f & 15;
      float4 v = *(const float4*)(Wm + (size_t)row * DM + kc + kk * 4);
      *(float4*)&wsh[row][kk * 4] = v;
    }
    __syncthreads();
#pragma unroll 4
    for (int k4 = 0; k4 < 16; ++k4) {
      float4 a0 = *(const float4*)&fs[r0][k4 * 4];
      float4 a1 = *(const float4*)&fs[r1][k4 * 4];
#pragma unroll
      for (int jj = 0; jj < 12; ++jj) {
        float4 w = *(const float4*)&wsh[jg * 12 + jj][k4 * 4];
        acc0[jj] += a0.x * w.x + a0.y * w.y + a0.z * w.z + a0.w * w.w;
        acc1[jj] += a1.x * w.x + a1.y * w.y + a1.z * w.z + a1.w * w.w;
      }
    }
  }
  const float sc = 0.044194173824159216f;
  size_t base0 = (size_t)(rowBase + r0) * NT + jg * 12;
  size_t base1 = (size_t)(rowBase + r1) * NT + jg * 12;
#pragma unroll
  for (int q = 0; q < 3; ++q) {
    float4 o0 = make_float4(acc0[q*4]*sc, acc0[q*4+1]*sc, acc0[q*4+2]*sc, acc0[q*4+3]*sc);
    float4 o1 = make_float4(acc1[q*4]*sc, acc1[q*4+1]*sc, acc1[q*4+2]*sc, acc1[q*4+3]*sc);
    *(float4*)(out + base0 + q*4) = o0;
    *(float4*)(out + base1 + q*4) = o1;
  }
}

// ---------------- K2: gold-path score per batch ----------------
__global__ __launch_bounds__(256) void k_score(const float* __restrict__ tg,
                                               const int* __restrict__ y,
                                               const unsigned char* __restrict__ mask,
                                               const float* __restrict__ trans,
                                               float* __restrict__ scoreOut) {
  const int b = blockIdx.x, t = threadIdx.x;
  const int* yb = y + (size_t)b * S_;
  const unsigned char* mbp = mask + (size_t)b * S_;
  float part = 0.f;
  int cnt = 0;
  for (int s = t; s < S_; s += 256) {
    int ys = yb[s];
    int ms = mbp[s];
    float bm = ms ? 0.f : 1.f;
    int yy = ms ? 0 : ys;
    part += tg[((size_t)b * S_ + s) * NT + yy] * bm;
    if (s >= 1) part += trans[yb[s - 1] * TT + ys] * bm;
    cnt += ms ? 1 : 0;
  }
  for (int d = 1; d < 64; d <<= 1) {
    part += __shfl_xor(part, d);
    cnt += __shfl_xor(cnt, d);
  }
  __shared__ float pw[4];
  __shared__ int cw[4];
  int wid = t >> 6;
  if ((t & 63) == 0) { pw[wid] = part; cw[wid] = cnt; }
  __syncthreads();
  if (t == 0) {
    float tot = pw[0] + pw[1] + pw[2] + pw[3];
    int c = cw[0] + cw[1] + cw[2] + cw[3];
    int L = S_ - 1 - c;
    tot += trans[NT * TT + yb[0]];
    tot += trans[yb[L] * TT + (NT + 1)];
    scoreOut[b] = tot;
  }
}

// ---------------- K3: single-wave serial scans ----------------
// blocks 0..63: forward scan in LINEAR domain (deferred logs)
// blocks 64..127: Viterbi VALUE pass only (argmax deferred to k_idx)
__global__ __launch_bounds__(64) void k_scan(const float* __restrict__ tg,
                                             const unsigned char* __restrict__ mask,
                                             const float* __restrict__ trans,
                                             const float* __restrict__ score,
                                             float* __restrict__ Mbuf,
                                             int* __restrict__ nowbuf,
                                             float* __restrict__ out) {
  __shared__ float bmL[S_ + 4];
  __shared__ float rbuf[256];

  const int t = threadIdx.x;
  const bool isV = blockIdx.x >= B_;
  const int b = isV ? (blockIdx.x - B_) : blockIdx.x;
  const int jc = (t < NT) ? t : (NT - 1);
  const float* tgb = tg + (size_t)b * S_ * NT;

  int cnt = 0;
  for (int m = t; m < S_; m += 64) {
    unsigned char mv = mask[(size_t)b * S_ + m];
    bmL[m] = mv ? 0.f : 1.f;
    cnt += mv ? 1 : 0;
  }
  if (t < 4) bmL[S_ + t] = 0.f;
#pragma unroll
  for (int d = 1; d < 64; d <<= 1) cnt += __shfl_xor(cnt, d);
  const int L = S_ - 1 - cnt;
  __syncthreads();

  if (!isV) {
    // ---------- forward, linear domain ----------
    float Ecol[NT];
#pragma unroll
    for (int i = 0; i < NT; ++i) Ecol[i] = __expf(trans[i * TT + jc]);
    float p = __expf(trans[NT * TT + jc]);  // exp(start_j)
    float ec = tgb[jc];
    float en = tgb[NT + jc];
    float m0r = bmL[0], m1r = bmL[1];
    for (int s = 0; s < S_; ++s) {
      float pe = p * __expf(ec * m0r);
      int m1b = __builtin_amdgcn_readfirstlane(__float_as_int(m1r));
      float Z;
      if (m1b != 0) {
        float z0 = 0.f, z1 = 0.f, z2 = 0.f, z3 = 0.f;
#pragma unroll
        for (int i = 0; i < NT; i += 4) {
          z0 = fmaf(rl(pe, i + 0), Ecol[i + 0], z0);
          z1 = fmaf(rl(pe, i + 1), Ecol[i + 1], z1);
          z2 = fmaf(rl(pe, i + 2), Ecol[i + 2], z2);
          z3 = fmaf(rl(pe, i + 3), Ecol[i + 3], z3);
        }
        Z = (z0 + z1) + (z2 + z3);
      } else {
        float vv = (t < NT) ? pe : 0.f;
#pragma unroll
        for (int d = 1; d < 64; d <<= 1) vv += __shfl_xor(vv, d);
        Z = vv;
      }
      p = Z;
      if ((s & 3) == 3) {
        float M = p;
#pragma unroll
        for (int d = 1; d < 64; d <<= 1) M = fmaxf(M, __shfl_xor(M, d));
        float r = __builtin_amdgcn_rcpf(M);  // any positive scalar works; we log r itself
        p *= r;
        if (t == 0) rbuf[s >> 2] = r;
      }
      ec = en;
      int s2 = (s + 2 < S_) ? (s + 2) : (S_ - 1);
      en = tgb[(size_t)s2 * NT + jc];
      m0r = m1r;
      m1r = bmL[s + 2];
    }
    // deferred logs: C = -sum log(r_k)
    float ls = 0.f;
#pragma unroll
    for (int k = 0; k < 4; ++k) ls += __logf(rbuf[t + 64 * k]);
#pragma unroll
    for (int d = 1; d < 64; d <<= 1) ls += __shfl_xor(ls, d);
    float v = (t < NT) ? p * __expf(trans[t * TT + (NT + 1)]) : 0.f;
#pragma unroll
    for (int d = 1; d < 64; d <<= 1) v += __shfl_xor(v, d);
    if (t == 0) out[b] = __logf(v) - ls - score[b];
  } else {
    // ---------- Viterbi value pass ----------
    float Tcol[NT];
#pragma unroll
    for (int i = 0; i < NT; ++i) Tcol[i] = trans[i * TT + jc];
    float* Mb = Mbuf + (size_t)b * S_ * NT;
    float best = trans[NT * TT + jc] + tgb[jc];
    float fin = best;  // valid if L==0
    float ec = tgb[NT + jc];
    float en = tgb[2 * NT + jc];
    for (int s = 1; s < S_; ++s) {
      float c[NT];
#pragma unroll
      for (int i = 0; i < NT; ++i) c[i] = rl(best, i) + Tcol[i];
      float u[16];
#pragma unroll
      for (int k = 0; k < 16; ++k)
        u[k] = fmaxf(fmaxf(c[3 * k], c[3 * k + 1]), c[3 * k + 2]);
      float w0 = fmaxf(fmaxf(u[0], u[1]), u[2]);
      float w1 = fmaxf(fmaxf(u[3], u[4]), u[5]);
      float w2 = fmaxf(fmaxf(u[6], u[7]), u[8]);
      float w3 = fmaxf(fmaxf(u[9], u[10]), u[11]);
      float w4 = fmaxf(fmaxf(u[12], u[13]), u[14]);
      float w5 = u[15];
      float x0 = fmaxf(fmaxf(w0, w1), w2);
      float x1 = fmaxf(fmaxf(w3, w4), w5);
      float M = fmaxf(x0, x1);
      Mb[(size_t)s * NT + jc] = M;  // pre-emit max (dup writes from idle lanes: same value)
      float bnew = M + ec;
      fin = (s == L) ? bnew : fin;
      best = bnew;
      ec = en;
      int s2 = (s + 2 < S_) ? (s + 2) : (S_ - 1);
      en = tgb[(size_t)s2 * NT + jc];
    }
    float v = (t < NT) ? (fin + trans[t * TT + (NT + 1)]) : -3.0e38f;
    float M = v;
#pragma unroll
    for (int d = 1; d < 64; d <<= 1) M = fmaxf(M, __shfl_xor(M, d));
    unsigned long long ball = __ballot(v == M);
    int now0 = __ffsll(ball) - 1;
    if (t == 0) nowbuf[b] = now0;
  }
}

// ---------------- K4: parallel argmax recompute (bit-exact replay) ----------------
// grid (64, 8), block 256: thread handles s = by*128 + (t>>1), half the j range.
__global__ __launch_bounds__(256) void k_idx(const float* __restrict__ tg,
                                             const float* __restrict__ Mbuf,
                                             const float* __restrict__ trans,
                                             unsigned char* __restrict__ idxbuf) {
  __shared__ float TshT[NT][NT];  // TshT[j][i] = trans[i][j]
  const int t = threadIdx.x;
  const int b = blockIdx.x;
  for (int k = t; k < NT * NT; k += 256) {
    int i = k / NT, j = k - i * NT;
    TshT[j][i] = trans[i * TT + j];
  }
  __syncthreads();
  const int s = blockIdx.y * 128 + (t >> 1);
  const int jh = (t & 1) * 24;
  if (s < 1) return;
  const float* tgb = tg + (size_t)b * S_ * NT;
  const float* Mb = Mbuf + (size_t)b * S_ * NT;
  float bprev[NT];
  if (s == 1) {
#pragma unroll
    for (int i = 0; i < NT; ++i) bprev[i] = trans[NT * TT + i] + tgb[i];
  } else {
#pragma unroll
    for (int i = 0; i < NT; ++i)
      bprev[i] = Mb[(size_t)(s - 1) * NT + i] + tgb[(size_t)(s - 1) * NT + i];
  }
  unsigned char* ob = idxbuf + ((size_t)b * S_ + s) * NT + jh;
#pragma unroll 4
  for (int jj = 0; jj < 24; ++jj) {
    int j = jh + jj;
    float M = Mb[(size_t)s * NT + j];
    int idx = 0;
#pragma unroll
    for (int i = NT - 1; i >= 0; --i) {
      float cc = bprev[i] + TshT[j][i];
      idx = (cc == M) ? i : idx;
    }
    ob[jj] = (unsigned char)idx;
  }
}

// ---------------- K5: backtrack via chunked pointer jumping ----------------
__global__ __launch_bounds__(1024) void k_btrack(const unsigned char* __restrict__ idxbuf,
                                                 const unsigned char* __restrict__ mask,
                                                 const int* __restrict__ nowbuf,
                                                 float* __restrict__ out) {
  __shared__ unsigned char idxL[S_][NT];
  __shared__ unsigned char mapc[16][NT];
  __shared__ int ELs[16];
  __shared__ int cnt_sh;
  const int t = threadIdx.x;
  const int b = blockIdx.x;
  if (t == 0) cnt_sh = 0;
  __syncthreads();
  // stage idx table (48B per row, dword loads)
  {
    const unsigned int* src = (const unsigned int*)(idxbuf + (size_t)b * S_ * NT);
    unsigned int* dst = (unsigned int*)&idxL[t][0];
#pragma unroll
    for (int k = 0; k < 12; ++k) dst[k] = src[(size_t)t * 12 + k];
  }
  int mv = mask[(size_t)b * S_ + t] ? 1 : 0;
  unsigned long long bal = __ballot(mv);
  int wcnt = __popcll(bal);
  if ((t & 63) == 0 && wcnt) atomicAdd(&cnt_sh, wcnt);
  __syncthreads();
  const int L = S_ - 1 - cnt_sh;
  const int now0 = nowbuf[b];
  // phase 1: 16 chunks x 48 tags
  if (t < 16 * NT) {
    const int c = t / NT;
    const int g = t - c * NT;
    int cur = g;
    const int top = (c == 15) ? (S_ - 1) : (c + 1) * 64;
    const int base = c * 64;
    for (int m = top; m > base; --m) {
      if (m <= L) cur = idxL[m][cur];
    }
    mapc[c][g] = (unsigned char)cur;
  }
  __syncthreads();
  // phase 2: chunk entry tags
  if (t == 0) {
    int e = now0;
    ELs[15] = e;
    for (int c2 = 15; c2 >= 1; --c2) {
      e = mapc[c2][e];
      ELs[c2 - 1] = e;
    }
  }
  __syncthreads();
  // phase 3: re-walk per chunk, write path
  float* pathOut = out + B_ + (size_t)b * S_;
  if (t < 16) {
    const int c = t;
    const int top = (c == 15) ? (S_ - 1) : (c + 1) * 64;
    const int base = c * 64;
    int cu = ELs[c];
    for (int m = top; m > base; --m) {
      if (m <= L) cu = idxL[m][cu];
      int pos = m - 1;
      pathOut[pos] = (pos > L) ? -1.0f : (float)cu;
    }
  }
  if (t == 0) pathOut[S_ - 1] = (L == S_ - 1) ? (float)now0 : -1.0f;
}

extern "C" void kernel_launch(void* const* d_in, const int* in_sizes, int n_in,
                              void* d_out, int out_size, void* d_ws, size_t ws_size,
                              hipStream_t stream) {
  const float* F = (const float*)d_in[0];
  const int* y = (const int*)d_in[1];
  const unsigned char* mask = (const unsigned char*)d_in[2];
  const float* Wm = (const float*)d_in[3];
  const float* trans = (const float*)d_in[4];
  float* out = (float*)d_out;

  const size_t NTG = (size_t)B_ * S_ * NT;  // 3,145,728
  float* tg = (float*)d_ws;
  float* score = tg + NTG;
  float* Mbuf = score + 64;
  int* nowbuf = (int*)(Mbuf + NTG);
  unsigned char* idxbuf = (unsigned char*)(nowbuf + 64);

  k_tagvec<<<dim3((B_ * S_) / 128), dim3(256), 0, stream>>>(F, Wm, tg);
  k_score<<<dim3(B_), dim3(256), 0, stream>>>(tg, y, mask, trans, score);
  k_scan<<<dim3(2 * B_), dim3(64), 0, stream>>>(tg, mask, trans, score, Mbuf, nowbuf, out);
  k_idx<<<dim3(B_, 8), dim3(256), 0, stream>>>(tg, Mbuf, trans, idxbuf);
  k_btrack<<<dim3(B_), dim3(1024), 0, stream>>>(idxbuf, mask, nowbuf, out);
}